// Round 6
// baseline (36.536 us; speedup 1.0000x reference)
//
#include <hip/hip_runtime.h>

// eTofts model: B=8, T=60, H=W=256.
//   params[B,3,H,W], Cp[B,T], S0[B,1,H,W], T1[B,1,H,W] -> St[B,T,H,W] fp32
// True traffic: 125.8 MB out + ~10.5 MB in => ~19.5 us floor at 7 TB/s.
//
// R5 lesson: plain stores regress vs nt (35.5 vs 33.1) -> no L3 absorption.
// Remaining theory: write MLP. Fill kernel (7 TB/s, 3 waves/CU) keeps ~63KB
// of stores in flight per wave via back-to-back issue; we interleaved 4
// stores with ~450cy of exp/rcp -> ~32-64KB in flight per CU, right at the
// latency*rate knee -> 4-5 TB/s. Fix: compute all 15 frames into registers,
// then burst all 15 nt stores back-to-back (sched_barrier pins the phase
// split). Blocks pipeline per CU: block n computes while n-1's burst drains.

#define N_TIME 60
#define HW (256 * 256)
#define CHUNKS 4
#define CHUNK_LEN (N_TIME / CHUNKS)   // 15

typedef float f32x4 __attribute__((ext_vector_type(4)));

__global__ __launch_bounds__(256) void etofts_kernel(
    const float* __restrict__ params,  // [B,3,H,W]
    const float* __restrict__ Cp,      // [B,T]
    const float* __restrict__ S0,      // [B,1,H,W]
    const float* __restrict__ T1,      // [B,1,H,W]
    float* __restrict__ out)           // [B,T,H,W]
{
    const float DT     = 5.0f;
    const float TR     = 5.0f;
    const float EPS    = 1e-8f;
    const float COS_FA = 0.9848077530122081f;            // cos(10 deg)
    const float QC2    = 0.0225f * 1.4426950408889634f;  // (R1*TR/1000)*log2(e)

    // 2048 blocks: b = bx>>8, chunk = (bx>>6)&3, blk = bx&63. All block-
    // uniform -> Cp loads are scalar s_load.
    const int bx    = blockIdx.x;
    const int b     = bx >> 8;
    const int chunk = (bx >> 6) & 3;
    const int blk   = bx & 63;
    const int pix   = (blk * 256 + threadIdx.x) * 4;

    const size_t plane = (size_t)b * HW + pix;

    const float4 kt4 = *reinterpret_cast<const float4*>(params + ((size_t)b * 3 + 0) * HW + pix);
    const float4 vp4 = *reinterpret_cast<const float4*>(params + ((size_t)b * 3 + 1) * HW + pix);
    const float4 ve4 = *reinterpret_cast<const float4*>(params + ((size_t)b * 3 + 2) * HW + pix);
    const float4 s04 = *reinterpret_cast<const float4*>(S0 + plane);
    const float4 t14 = *reinterpret_cast<const float4*>(T1 + plane);

    float Kt[4], vp[4], decay[4], Ce[4], eP[4], Kc[4], d0[4], d1[4];
    {
        const float ktv[4] = {kt4.x, kt4.y, kt4.z, kt4.w};
        const float vpv[4] = {vp4.x, vp4.y, vp4.z, vp4.w};
        const float vev[4] = {ve4.x, ve4.y, ve4.z, ve4.w};
        const float s0v[4] = {s04.x, s04.y, s04.z, s04.w};
        const float t1v[4] = {t14.x, t14.y, t14.z, t14.w};
#pragma unroll
        for (int i = 0; i < 4; ++i) {
            const float Ktrans = ktv[i] * (1.0f / 60.0f);
            const float Kep    = __fdividef(Ktrans, vev[i] + EPS);
            Kt[i]    = Ktrans;
            vp[i]    = vpv[i];
            decay[i] = __expf(-Kep * DT);
            const float P = __fdividef(TR, t1v[i] + EPS);
            const float e = __expf(-P);
            eP[i] = e;
            Kc[i] = (1.0f - COS_FA * e) * s0v[i];
            const float den1 = 1.0f - e;
            d0[i] = den1 + EPS;              // den = d0 - d1*ePQ
            d1[i] = COS_FA * den1;
            Ce[i] = 0.0f;
        }
    }

    const float* cp_row = Cp + b * N_TIME;   // uniform -> s_load
    const int t0 = chunk * CHUNK_LEN;

    // Replay the fma-only recurrence up to this chunk's start (<=45 iters).
    for (int t = 0; t < t0; ++t) {
        const float cpdt = cp_row[t] * DT;
#pragma unroll
        for (int i = 0; i < 4; ++i) Ce[i] = Ce[i] * decay[i] + cpdt;
    }

    // Phase 1: compute ALL 15 frames into registers (static indexing only).
    f32x4 buf[CHUNK_LEN];
#pragma unroll
    for (int k = 0; k < CHUNK_LEN; ++k) {
        const float cp   = cp_row[t0 + k];
        const float cpdt = cp * DT;
        float st[4];
#pragma unroll
        for (int i = 0; i < 4; ++i) {
            Ce[i] = Ce[i] * decay[i] + cpdt;
            const float Ct  = vp[i] * cp + Kt[i] * Ce[i];
            const float ePQ = eP[i] * exp2f(-QC2 * Ct);
            const float num = Kc[i] - Kc[i] * ePQ;
            const float den = d0[i] - d1[i] * ePQ;
            st[i] = __fdividef(num, den);
        }
        buf[k] = (f32x4){st[0], st[1], st[2], st[3]};
    }

    // Pin the phase split: no store issued before all compute done, so the
    // 15 stores go out back-to-back (fill-style burst, 15 KB/wave in flight).
    __builtin_amdgcn_sched_barrier(0);

    float* outp = out + ((size_t)(b * N_TIME + t0)) * HW + pix;
#pragma unroll
    for (int k = 0; k < CHUNK_LEN; ++k) {
        __builtin_nontemporal_store(buf[k], reinterpret_cast<f32x4*>(outp + (size_t)k * HW));
    }
}

extern "C" void kernel_launch(void* const* d_in, const int* in_sizes, int n_in,
                              void* d_out, int out_size, void* d_ws, size_t ws_size,
                              hipStream_t stream) {
    const float* params = (const float*)d_in[0];
    const float* Cp     = (const float*)d_in[1];
    const float* S0     = (const float*)d_in[2];
    const float* T1     = (const float*)d_in[3];
    float* out          = (float*)d_out;

    const int grid = 8 * CHUNKS * 64;  // 2048 blocks
    etofts_kernel<<<grid, 256, 0, stream>>>(params, Cp, S0, T1, out);
}